// Round 1
// baseline (2255.421 us; speedup 1.0000x reference)
//
#include <hip/hip_runtime.h>
#include <math.h>

#define TP 16        // points per block
#define HH 256       // hidden width
#define KPAD 260     // padded feature stride in LDS (multiple of 4)
#define NTHREADS 128

__global__ __launch_bounds__(NTHREADS)
void capnn_kernel(const float* __restrict__ inp,
                  const float* __restrict__ W0, const float* __restrict__ b0,
                  const float* __restrict__ W1, const float* __restrict__ b1,
                  const float* __restrict__ W2, const float* __restrict__ b2,
                  const float* __restrict__ W3, const float* __restrict__ b3,
                  const float* __restrict__ W4, const float* __restrict__ b4,
                  const float* __restrict__ p_lgr, const float* __restrict__ p_lcc,
                  const float* __restrict__ p_lil,
                  const float* __restrict__ in_mean, const float* __restrict__ in_std,
                  const float* __restrict__ tgt_mean, const float* __restrict__ tgt_std,
                  float* __restrict__ out, int N)
{
    // act[stream][point][feature]: stream 0=value, 1=d/dtn, 2=d2/dtn2
    __shared__ float act[3][TP][KPAD];
    __shared__ float sn_sh[TP], tn_sh[TP];

    const int tid = threadIdx.x;
    const int j0 = tid;            // output feature row 1
    const int j1 = tid + NTHREADS; // output feature row 2
    const int pbase = blockIdx.x * TP;

    // ---- PDE scalars (uniform, L2-cached loads) ----
    const float r   = expf(-p_lgr[0]);
    const float Kc  = 0.2f + 0.8f * (1.f / (1.f + expf(-p_lcc[0])));
    const float Cc  = 0.1f * (1.f / (1.f + expf(-p_lil[0])));
    const float kci = 1.f / (Kc - Cc);
    const float tm  = tgt_mean[0], ts = tgt_std[0];

    // ---- stage normalized inputs for the 16 points ----
    if (tid < TP) {
        int pg = pbase + tid;
        float s = 0.f, t = 0.f;
        if (pg < N) { s = inp[2 * pg]; t = inp[2 * pg + 1]; }
        sn_sh[tid] = (s - in_mean[0]) / (in_std[0] + 1e-8f);
        tn_sh[tid] = (t - in_mean[1]) / (in_std[1] + 1e-8f);
    }
    __syncthreads();

    // ---- layer 0: 2 -> 256 (z' = W0[:,1], z'' = 0) ----
    {
        float w00 = W0[2 * j0], w01 = W0[2 * j0 + 1], bb0 = b0[j0];
        float w10 = W0[2 * j1], w11 = W0[2 * j1 + 1], bb1 = b0[j1];
        #pragma unroll
        for (int p = 0; p < TP; ++p) {
            float sn = sn_sh[p], tn = tn_sh[p];
            {
                float z  = fmaf(w00, sn, fmaf(w01, tn, bb0));
                float a  = tanhf(z);
                float g  = 1.f - a * a;
                float d1 = g * w01;
                float d2 = -2.f * a * d1 * w01;
                act[0][p][j0] = a; act[1][p][j0] = d1; act[2][p][j0] = d2;
            }
            {
                float z  = fmaf(w10, sn, fmaf(w11, tn, bb1));
                float a  = tanhf(z);
                float g  = 1.f - a * a;
                float d1 = g * w11;
                float d2 = -2.f * a * d1 * w11;
                act[0][p][j1] = a; act[1][p][j1] = d1; act[2][p][j1] = d2;
            }
        }
    }
    __syncthreads();

    // ---- layers 1..3: 256 -> 256 with tanh, 2nd-order forward prop ----
    const float* Ws[3] = { W1, W2, W3 };
    const float* bs[3] = { b1, b2, b3 };
    for (int L = 0; L < 3; ++L) {
        const float* __restrict__ W  = Ws[L];
        const float* __restrict__ bb = bs[L];
        float av0[TP], a10[TP], a20[TP];
        float av1[TP], a11[TP], a21[TP];
        float bj0 = bb[j0], bj1 = bb[j1];
        #pragma unroll
        for (int p = 0; p < TP; ++p) {
            av0[p] = bj0; a10[p] = 0.f; a20[p] = 0.f;
            av1[p] = bj1; a11[p] = 0.f; a21[p] = 0.f;
        }
        const float* Wr0 = W + j0 * HH;
        const float* Wr1 = W + j1 * HH;
        for (int k = 0; k < HH; k += 4) {
            float4 w0 = *(const float4*)(Wr0 + k);
            float4 w1 = *(const float4*)(Wr1 + k);
            #pragma unroll
            for (int p = 0; p < TP; ++p) {
                // wave-uniform broadcast reads (conflict-free)
                float4 xv = *(const float4*)&act[0][p][k];
                float4 x1 = *(const float4*)&act[1][p][k];
                float4 x2 = *(const float4*)&act[2][p][k];
                av0[p] += w0.x*xv.x + w0.y*xv.y + w0.z*xv.z + w0.w*xv.w;
                a10[p] += w0.x*x1.x + w0.y*x1.y + w0.z*x1.z + w0.w*x1.w;
                a20[p] += w0.x*x2.x + w0.y*x2.y + w0.z*x2.z + w0.w*x2.w;
                av1[p] += w1.x*xv.x + w1.y*xv.y + w1.z*xv.z + w1.w*xv.w;
                a11[p] += w1.x*x1.x + w1.y*x1.y + w1.z*x1.z + w1.w*x1.w;
                a21[p] += w1.x*x2.x + w1.y*x2.y + w1.z*x2.z + w1.w*x2.w;
            }
        }
        __syncthreads();  // everyone done reading act before overwrite
        #pragma unroll
        for (int p = 0; p < TP; ++p) {
            {
                float a  = tanhf(av0[p]);
                float g  = 1.f - a * a;
                float d1 = g * a10[p];
                float d2 = g * a20[p] - 2.f * a * d1 * a10[p];
                act[0][p][j0] = a; act[1][p][j0] = d1; act[2][p][j0] = d2;
            }
            {
                float a  = tanhf(av1[p]);
                float g  = 1.f - a * a;
                float d1 = g * a11[p];
                float d2 = g * a21[p] - 2.f * a * d1 * a11[p];
                act[0][p][j1] = a; act[1][p][j1] = d1; act[2][p][j1] = d2;
            }
        }
        __syncthreads();
    }

    // ---- head: 256 -> 1, then Verhulst residuals ----
    const int p  = tid >> 3;   // 16 points
    const int t8 = tid & 7;    // 8 threads per point
    float sv = 0.f, s1 = 0.f, s2 = 0.f;
    for (int k = t8; k < HH; k += 8) {
        float w = W4[k];
        sv += w * act[0][p][k];
        s1 += w * act[1][p][k];
        s2 += w * act[2][p][k];
    }
    #pragma unroll
    for (int m = 4; m >= 1; m >>= 1) {
        sv += __shfl_xor(sv, m, 8);
        s1 += __shfl_xor(s1, m, 8);
        s2 += __shfl_xor(s2, m, 8);
    }
    if (t8 == 0) {
        int pg = pbase + p;
        if (pg < N) {
            float U   = (sv + b4[0]) * ts + tm;
            float Ut  = s1 * ts;
            float Utt = s2 * ts;
            float Um  = U - Cc;
            float G   = r * Um * (1.f - Um * kci);
            float Gt  = r * Ut * (1.f - 2.f * Um * kci);
            out[pg]         = U;        // U
            out[N + pg]     = Ut - G;   // F
            out[2 * N + pg] = Utt - Gt; // F_t
        }
    }
}

extern "C" void kernel_launch(void* const* d_in, const int* in_sizes, int n_in,
                              void* d_out, int out_size, void* d_ws, size_t ws_size,
                              hipStream_t stream) {
    const float* inp   = (const float*)d_in[0];
    const float* W0    = (const float*)d_in[1];
    const float* b0    = (const float*)d_in[2];
    const float* W1    = (const float*)d_in[3];
    const float* b1    = (const float*)d_in[4];
    const float* W2    = (const float*)d_in[5];
    const float* b2    = (const float*)d_in[6];
    const float* W3    = (const float*)d_in[7];
    const float* b3    = (const float*)d_in[8];
    const float* W4    = (const float*)d_in[9];
    const float* b4    = (const float*)d_in[10];
    const float* lgr   = (const float*)d_in[11];
    const float* lcc   = (const float*)d_in[12];
    const float* lil   = (const float*)d_in[13];
    const float* imean = (const float*)d_in[14];
    const float* istd  = (const float*)d_in[15];
    const float* tmean = (const float*)d_in[16];
    const float* tstd  = (const float*)d_in[17];

    const int N = in_sizes[0] / 2;           // 65536 points
    const int grid = (N + TP - 1) / TP;      // 4096 blocks

    hipLaunchKernelGGL(capnn_kernel, dim3(grid), dim3(NTHREADS), 0, stream,
                       inp, W0, b0, W1, b1, W2, b2, W3, b3, W4, b4,
                       lgr, lcc, lil, imean, istd, tmean, tstd,
                       (float*)d_out, N);
}

// Round 2
// 283.858 us; speedup vs baseline: 7.9456x; 7.9456x over previous
//
#include <hip/hip_runtime.h>
#include <math.h>

typedef short s8v __attribute__((ext_vector_type(8)));
typedef float f4v __attribute__((ext_vector_type(4)));

#define HH 256
#define TP 16          // points per block
#define NROW 48        // 3 streams * TP rows
#define RS 264         // LDS row stride in shorts (pad: 528B = 33*16B -> conflict-free b128)
#define NTHREADS 256

// ---- bf16 split helpers (truncation split: x = hi + lo, err ~2^-16) ----
__device__ __forceinline__ unsigned short bf_hi(float x) {
    union { float f; unsigned u; } v; v.f = x;
    return (unsigned short)(v.u >> 16);
}
__device__ __forceinline__ float bf_hi_f(float x) {
    union { float f; unsigned u; } v; v.f = x;
    v.u &= 0xFFFF0000u;
    return v.f;
}
__device__ __forceinline__ float bf2f(unsigned short h) {
    union { unsigned u; float f; } v; v.u = ((unsigned)h) << 16;
    return v.f;
}
__device__ __forceinline__ void put_hl(unsigned short* Ahi, unsigned short* Alo,
                                       int idx, float x) {
    Ahi[idx] = bf_hi(x);
    Alo[idx] = bf_hi(x - bf_hi_f(x));
}

// ---- prep: convert W1..W3 to hi/lo bf16 planes in B-fragment-linear order ----
// frag layout: for (nt, ks): lane l holds W[nt*16 + (l&15)][ks*32 + (l>>4)*8 + j], j=0..7
// dst short index within plane = ((nt*8 + ks)*64 + l)*8 + j
__global__ __launch_bounds__(256)
void prep_weights(const float* __restrict__ W1, const float* __restrict__ W2,
                  const float* __restrict__ W3, unsigned short* __restrict__ ws)
{
    int tid = blockIdx.x * 256 + threadIdx.x;     // 0 .. 3*65536-1
    int layer = tid >> 16;
    int rem = tid & 65535;
    const float* W = (layer == 0) ? W1 : (layer == 1) ? W2 : W3;
    int j  = rem & 7;
    int l  = (rem >> 3) & 63;
    int ks = (rem >> 9) & 7;
    int nt = (rem >> 12) & 15;
    int n = nt * 16 + (l & 15);
    int k = ks * 32 + ((l >> 4) << 3) + j;
    float x = W[n * HH + k];
    unsigned short* base = ws + layer * 131072;   // per-layer: 65536 hi + 65536 lo shorts
    base[rem] = bf_hi(x);
    base[65536 + rem] = bf_hi(x - bf_hi_f(x));
}

// ---- main fused kernel ----
__global__ __launch_bounds__(NTHREADS, 3)
void capnn_mfma(const float* __restrict__ inp,
                const float* __restrict__ W0, const float* __restrict__ b0,
                const float* __restrict__ b1, const float* __restrict__ b2,
                const float* __restrict__ b3,
                const float* __restrict__ W4, const float* __restrict__ b4,
                const float* __restrict__ lgr, const float* __restrict__ lcc,
                const float* __restrict__ lil,
                const float* __restrict__ imean, const float* __restrict__ istd,
                const float* __restrict__ tmean, const float* __restrict__ tstd,
                const unsigned short* __restrict__ wsW,
                float* __restrict__ out, int N)
{
    __shared__ __align__(16) unsigned short Ahi[NROW * RS];
    __shared__ __align__(16) unsigned short Alo[NROW * RS];
    __shared__ float sn_sh[TP], tn_sh[TP];
    __shared__ float head_s[NROW];

    const int tid  = threadIdx.x;
    const int lane = tid & 63;
    const int w    = tid >> 6;       // wave id: owns N cols [w*64, w*64+64)
    const int m16  = lane & 15;
    const int q    = lane >> 4;      // k-quad for A/B frags; row-quad for C
    const int pbase = blockIdx.x * TP;

    // ---- stage normalized inputs ----
    if (tid < TP) {
        int pg = pbase + tid;
        float s = 0.f, t = 0.f;
        if (pg < N) { s = inp[2 * pg]; t = inp[2 * pg + 1]; }
        sn_sh[tid] = (s - imean[0]) / (istd[0] + 1e-8f);
        tn_sh[tid] = (t - imean[1]) / (istd[1] + 1e-8f);
    }
    __syncthreads();

    // ---- layer 0: 2 -> 256 (z' = W0[:,1], z'' = 0); thread owns col n = tid ----
    {
        const int n = tid;
        const float w00 = W0[2 * n], w01 = W0[2 * n + 1], bb = b0[n];
        #pragma unroll 4
        for (int p = 0; p < TP; ++p) {
            float z = fmaf(w00, sn_sh[p], fmaf(w01, tn_sh[p], bb));
            float e = __expf(2.f * z);
            float a = 1.f - 2.f * __builtin_amdgcn_rcpf(e + 1.f);   // tanh(z)
            float g = 1.f - a * a;
            float d1 = g * w01;
            float d2 = -2.f * a * d1 * w01;
            put_hl(Ahi, Alo, (0 * TP + p) * RS + n, a);
            put_hl(Ahi, Alo, (1 * TP + p) * RS + n, d1);
            put_hl(Ahi, Alo, (2 * TP + p) * RS + n, d2);
        }
    }
    __syncthreads();

    // ---- layers 1..3: 48x256 = (48x256) x (256x256)^T via split-bf16 MFMA ----
    for (int L = 0; L < 3; ++L) {
        const unsigned short* __restrict__ Wlh = wsW + L * 131072;
        const unsigned short* __restrict__ Wll = Wlh + 65536;

        f4v acc[3][4];
        #pragma unroll
        for (int s = 0; s < 3; ++s)
            #pragma unroll
            for (int i = 0; i < 4; ++i)
                acc[s][i] = (f4v){0.f, 0.f, 0.f, 0.f};

        #pragma unroll 2
        for (int ks = 0; ks < 8; ++ks) {
            s8v ah[3], al[3];
            #pragma unroll
            for (int s = 0; s < 3; ++s) {
                int off = (s * TP + m16) * RS + ks * 32 + q * 8;
                ah[s] = *(const s8v*)&Ahi[off];
                al[s] = *(const s8v*)&Alo[off];
            }
            s8v bh[4], bl[4];
            #pragma unroll
            for (int i = 0; i < 4; ++i) {
                int off = ((((w * 4 + i) * 8 + ks) * 64) + lane) * 8;
                bh[i] = *(const s8v*)(Wlh + off);
                bl[i] = *(const s8v*)(Wll + off);
            }
            #pragma unroll
            for (int s = 0; s < 3; ++s)
                #pragma unroll
                for (int i = 0; i < 4; ++i)
                    acc[s][i] = __builtin_amdgcn_mfma_f32_16x16x32_bf16(ah[s], bh[i], acc[s][i], 0, 0, 0);
            #pragma unroll
            for (int s = 0; s < 3; ++s)
                #pragma unroll
                for (int i = 0; i < 4; ++i)
                    acc[s][i] = __builtin_amdgcn_mfma_f32_16x16x32_bf16(ah[s], bl[i], acc[s][i], 0, 0, 0);
            #pragma unroll
            for (int s = 0; s < 3; ++s)
                #pragma unroll
                for (int i = 0; i < 4; ++i)
                    acc[s][i] = __builtin_amdgcn_mfma_f32_16x16x32_bf16(al[s], bh[i], acc[s][i], 0, 0, 0);
        }
        __syncthreads();   // all waves done reading A before overwrite

        // ---- transform: C layout col=lane&15, row(point)=q*4+r; streams in same lane ----
        const float* __restrict__ bL = (L == 0) ? b1 : (L == 1) ? b2 : b3;
        #pragma unroll
        for (int i = 0; i < 4; ++i) {
            const int n = w * 64 + i * 16 + m16;
            const float bias = bL[n];
            #pragma unroll
            for (int r = 0; r < 4; ++r) {
                const int p = q * 4 + r;
                float z  = acc[0][i][r] + bias;
                float z1 = acc[1][i][r];
                float z2 = acc[2][i][r];
                float e = __expf(2.f * z);
                float a = 1.f - 2.f * __builtin_amdgcn_rcpf(e + 1.f);  // tanh
                float g = 1.f - a * a;
                float d1 = g * z1;
                float d2 = fmaf(g, z2, -2.f * a * d1 * z1);
                put_hl(Ahi, Alo, (0 * TP + p) * RS + n, a);
                put_hl(Ahi, Alo, (1 * TP + p) * RS + n, d1);
                put_hl(Ahi, Alo, (2 * TP + p) * RS + n, d2);
            }
        }
        __syncthreads();
    }

    // ---- head: 256 -> 1 per row (48 rows), fp32 from hi+lo ----
    if (tid < 192) {
        const int row = tid >> 2, sub = tid & 3;
        const int kbase = sub * 64;
        float sum = 0.f;
        #pragma unroll 2
        for (int jj = 0; jj < 8; ++jj) {
            int off = row * RS + kbase + jj * 8;
            s8v h8 = *(const s8v*)&Ahi[off];
            s8v l8 = *(const s8v*)&Alo[off];
            float4 wA = *(const float4*)(W4 + kbase + jj * 8);
            float4 wB = *(const float4*)(W4 + kbase + jj * 8 + 4);
            sum = fmaf(wA.x, bf2f((unsigned short)h8[0]) + bf2f((unsigned short)l8[0]), sum);
            sum = fmaf(wA.y, bf2f((unsigned short)h8[1]) + bf2f((unsigned short)l8[1]), sum);
            sum = fmaf(wA.z, bf2f((unsigned short)h8[2]) + bf2f((unsigned short)l8[2]), sum);
            sum = fmaf(wA.w, bf2f((unsigned short)h8[3]) + bf2f((unsigned short)l8[3]), sum);
            sum = fmaf(wB.x, bf2f((unsigned short)h8[4]) + bf2f((unsigned short)l8[4]), sum);
            sum = fmaf(wB.y, bf2f((unsigned short)h8[5]) + bf2f((unsigned short)l8[5]), sum);
            sum = fmaf(wB.z, bf2f((unsigned short)h8[6]) + bf2f((unsigned short)l8[6]), sum);
            sum = fmaf(wB.w, bf2f((unsigned short)h8[7]) + bf2f((unsigned short)l8[7]), sum);
        }
        sum += __shfl_xor(sum, 1);
        sum += __shfl_xor(sum, 2);
        if (sub == 0) head_s[row] = sum;
    }
    __syncthreads();

    // ---- Verhulst residuals + store ----
    if (tid < TP) {
        int pg = pbase + tid;
        if (pg < N) {
            float r_  = expf(-lgr[0]);
            float Kc  = 0.2f + 0.8f / (1.f + expf(-lcc[0]));
            float Cc  = 0.1f / (1.f + expf(-lil[0]));
            float kci = 1.f / (Kc - Cc);
            float ts = tstd[0], tm = tmean[0];
            float U   = (head_s[tid] + b4[0]) * ts + tm;
            float Ut  = head_s[TP + tid] * ts;
            float Utt = head_s[2 * TP + tid] * ts;
            float Um  = U - Cc;
            float G   = r_ * Um * (1.f - Um * kci);
            float Gt  = r_ * Ut * (1.f - 2.f * Um * kci);
            out[pg]         = U;
            out[N + pg]     = Ut - G;
            out[2 * N + pg] = Utt - Gt;
        }
    }
}

extern "C" void kernel_launch(void* const* d_in, const int* in_sizes, int n_in,
                              void* d_out, int out_size, void* d_ws, size_t ws_size,
                              hipStream_t stream) {
    const float* inp   = (const float*)d_in[0];
    const float* W0    = (const float*)d_in[1];
    const float* b0    = (const float*)d_in[2];
    const float* W1    = (const float*)d_in[3];
    const float* b1    = (const float*)d_in[4];
    const float* W2    = (const float*)d_in[5];
    const float* b2    = (const float*)d_in[6];
    const float* W3    = (const float*)d_in[7];
    const float* b3    = (const float*)d_in[8];
    const float* W4    = (const float*)d_in[9];
    const float* b4    = (const float*)d_in[10];
    const float* lgr   = (const float*)d_in[11];
    const float* lcc   = (const float*)d_in[12];
    const float* lil   = (const float*)d_in[13];
    const float* imean = (const float*)d_in[14];
    const float* istd  = (const float*)d_in[15];
    const float* tmean = (const float*)d_in[16];
    const float* tstd  = (const float*)d_in[17];

    unsigned short* wsW = (unsigned short*)d_ws;   // 3 layers * 256KB hi/lo planes

    const int N = in_sizes[0] / 2;                 // 65536 points
    const int gridMain = (N + TP - 1) / TP;        // 4096 blocks

    hipLaunchKernelGGL(prep_weights, dim3(768), dim3(256), 0, stream, W1, W2, W3, wsW);
    hipLaunchKernelGGL(capnn_mfma, dim3(gridMain), dim3(NTHREADS), 0, stream,
                       inp, W0, b0, b1, b2, b3, W4, b4,
                       lgr, lcc, lil, imean, istd, tmean, tstd,
                       wsW, (float*)d_out, N);
}